// Round 3
// baseline (517.192 us; speedup 1.0000x reference)
//
#include <hip/hip_runtime.h>
#include <hip/hip_bf16.h>
#include <math.h>
#include <stdint.h>

typedef __bf16 bf16;
typedef __attribute__((ext_vector_type(4))) float floatx4;
typedef __attribute__((ext_vector_type(8))) bf16 bf16x8;
typedef __attribute__((ext_vector_type(4))) bf16 bf16x4;

#define LDS_ASYNC16(gptr, lptr)                                                \
  __builtin_amdgcn_global_load_lds(                                            \
      (const __attribute__((address_space(1))) void*)(gptr),                   \
      (__attribute__((address_space(3))) void*)(lptr), 16, 0, 0)

// ---------------- elementwise fp32 -> bf16 ----------------
__global__ __launch_bounds__(256) void k_cvt(const float* __restrict__ in,
                                             bf16* __restrict__ out) {
  int i = (blockIdx.x * 256 + threadIdx.x) * 4;
  float4 v = *(const float4*)(in + i);
  bf16x4 o;
  o[0] = (bf16)v.x; o[1] = (bf16)v.y; o[2] = (bf16)v.z; o[3] = (bf16)v.w;
  *(bf16x4*)(out + i) = o;
}

// ---------------- merge two fp32 partials ----------------
__global__ __launch_bounds__(256) void k_merge(const float* __restrict__ a,
                                               const float* __restrict__ b,
                                               float* __restrict__ out) {
  int i = (blockIdx.x * 256 + threadIdx.x) * 4;
  float4 va = *(const float4*)(a + i);
  float4 vb = *(const float4*)(b + i);
  float4 o;
  o.x = va.x + vb.x; o.y = va.y + vb.y; o.z = va.z + vb.z; o.w = va.w + vb.w;
  *(float4*)(out + i) = o;
}

// ---------------- transpose + convert: in[K][N] f32 -> out[N][K] bf16 -------
__global__ __launch_bounds__(256) void k_transpose_cvt(const float* __restrict__ in,
                                                       bf16* __restrict__ out,
                                                       int K, int N) {
  __shared__ float tile[64][65];
  int k0 = blockIdx.y * 64, n0 = blockIdx.x * 64;
  int tid = threadIdx.x;
  int cg = tid & 15, rr = tid >> 4;
#pragma unroll
  for (int p = 0; p < 4; ++p) {
    int r = rr + p * 16;
    float4 v = *(const float4*)(in + (size_t)(k0 + r) * N + n0 + cg * 4);
    tile[r][cg * 4 + 0] = v.x; tile[r][cg * 4 + 1] = v.y;
    tile[r][cg * 4 + 2] = v.z; tile[r][cg * 4 + 3] = v.w;
  }
  __syncthreads();
#pragma unroll
  for (int p = 0; p < 4; ++p) {
    int n = rr + p * 16;
    bf16x4 o;
    o[0] = (bf16)tile[cg * 4 + 0][n];
    o[1] = (bf16)tile[cg * 4 + 1][n];
    o[2] = (bf16)tile[cg * 4 + 2][n];
    o[3] = (bf16)tile[cg * 4 + 3][n];
    *(bf16x4*)(out + (size_t)(n0 + n) * K + k0 + cg * 4) = o;
  }
}

// ---------------- GEMM split-K: A[M][K] bf16 @ B[N][K] bf16 -----------------
// 128x128 tile, BK=32, LDS chunk-swizzled (chunk' = c ^ ((row>>1)&3)) so
// fragment ds_read_b128 is 2-way (free) instead of 8-way conflicted.
__global__ __launch_bounds__(256) void k_gemm_bt(const bf16* __restrict__ A,
                                                 const bf16* __restrict__ B,
                                                 float* __restrict__ C,
                                                 int M, int N, int K, int ksplit) {
  __shared__ bf16 As[128 * 32];
  __shared__ bf16 Bs[128 * 32];
  int tid = threadIdx.x;
  int w = tid >> 6, lane = tid & 63;
  int lq = lane >> 4, l16 = lane & 15;
  int bm = blockIdx.y * 128, bn = blockIdx.x * 128;
  int wm = (w >> 1) * 64, wn = (w & 1) * 64;
  int kc = K / ksplit;
  int koff = blockIdx.z * kc;
  C += (size_t)blockIdx.z * M * N;
  floatx4 acc[4][4] = {};
  const bf16* Ab = A + (size_t)bm * K;
  const bf16* Bb = B + (size_t)bn * K;
  int srow = (lane >> 2);                               // 16 rows / instr
  int scol = (((lane & 3) ^ ((srow >> 1) & 3))) * 8;    // swizzled 16B chunk
  int sa = (l16 >> 1) & 3;                              // read-side swizzle

  for (int k0 = koff; k0 < koff + kc; k0 += 32) {
#pragma unroll
    for (int c = 0; c < 2; ++c) {
      int r = w * 32 + c * 16 + srow;
      LDS_ASYNC16(Ab + (size_t)r * K + k0 + scol, &As[(w * 32 + c * 16) * 32]);
      LDS_ASYNC16(Bb + (size_t)r * K + k0 + scol, &Bs[(w * 32 + c * 16) * 32]);
    }
    __syncthreads();
    bf16x8 af[4], bfr[4];
#pragma unroll
    for (int i = 0; i < 4; ++i)
      af[i] = *(const bf16x8*)&As[(wm + i * 16 + l16) * 32 + (lq ^ sa) * 8];
#pragma unroll
    for (int j = 0; j < 4; ++j)
      bfr[j] = *(const bf16x8*)&Bs[(wn + j * 16 + l16) * 32 + (lq ^ sa) * 8];
#pragma unroll
    for (int i = 0; i < 4; ++i)
#pragma unroll
      for (int j = 0; j < 4; ++j)
        acc[i][j] = __builtin_amdgcn_mfma_f32_16x16x32_bf16(af[i], bfr[j],
                                                            acc[i][j], 0, 0, 0);
    __syncthreads();
  }
  // C/D layout: col = lane&15, row = (lane>>4)*4 + reg  [m89-verified]
#pragma unroll
  for (int i = 0; i < 4; ++i)
#pragma unroll
    for (int j = 0; j < 4; ++j) {
      int m = bm + wm + i * 16 + lq * 4;
      int n = bn + wn + j * 16 + l16;
      float* cp = C + (size_t)m * N + n;
#pragma unroll
      for (int r = 0; r < 4; ++r) cp[(size_t)r * N] = acc[i][j][r];
    }
}

// ---------------- RoPE on Q and K heads of xqkv (sums 2 partials) -----------
__global__ __launch_bounds__(256) void k_rope(const float* __restrict__ xp0,
                                              const float* __restrict__ xp1,
                                              bf16* __restrict__ qb,
                                              bf16* __restrict__ kb,
                                              const int* __restrict__ seqstarts,
                                              const int* __restrict__ start_pos) {
  int t = blockIdx.x;
  int s = 0;
  for (int i = 1; i < 4; ++i) if (seqstarts[i] <= t) s = i;
  float pos = (float)(t - seqstarts[s] + start_pos[s]);
  for (int wk = threadIdx.x; wk < 40 * 64; wk += 256) {
    int hh = wk >> 6, j = wk & 63;
    size_t idx = ((size_t)t * 48 + hh) * 128 + 2 * j;
    float2 a0 = *(const float2*)(xp0 + idx);
    float2 a1 = *(const float2*)(xp1 + idx);
    float x1 = a0.x + a1.x;
    float x2 = a0.y + a1.y;
    float invf = exp2f(-(float)j * 0.20762050593045935f);
    float ang = pos * invf;
    float sv, cv;
    sincosf(ang, &sv, &cv);
    float r1 = x1 * cv - x2 * sv;
    float r2 = x1 * sv + x2 * cv;
    unsigned int u1 = (unsigned int)__builtin_bit_cast(unsigned short, (bf16)r1);
    unsigned int u2 = (unsigned int)__builtin_bit_cast(unsigned short, (bf16)r2);
    unsigned int pk = u1 | (u2 << 16);
    unsigned int* dst = (hh < 32)
        ? (unsigned int*)(qb + ((size_t)t * 32 + hh) * 128)
        : (unsigned int*)(kb + ((size_t)t * 8 + (hh - 32)) * 128);
    dst[j] = pk;
  }
}

// ---------------- assemble K: kall[hk][3072][128] bf16 ----------------
__global__ __launch_bounds__(256) void k_assemble_k(
    const bf16* __restrict__ xk, const float* __restrict__ ck,
    bf16* __restrict__ kall,
    const int* __restrict__ seqstarts, const int* __restrict__ kvstarts,
    const int* __restrict__ cachestarts, const int* __restrict__ start_pos) {
  int p = blockIdx.x;  // 0..3071
  int b = 0;
  for (int i = 1; i < 4; ++i) if (kvstarts[i] <= p) b = i;
  int pkv = p - kvstarts[b];
  int tid = threadIdx.x;
  int hk = tid >> 5, d4 = (tid & 31) * 4;
  bf16* dst = kall + ((size_t)hk * 3072 + p) * 128 + d4;
  if (pkv >= start_pos[b]) {
    int tn = seqstarts[b] + pkv - start_pos[b];
    *(bf16x4*)dst = *(const bf16x4*)(xk + ((size_t)tn * 8 + hk) * 128 + d4);
  } else {
    int ci = cachestarts[b] + pkv;
    float4 v = *(const float4*)(ck + ((size_t)ci * 8 + hk) * 128 + d4);
    bf16x4 o;
    o[0] = (bf16)v.x; o[1] = (bf16)v.y; o[2] = (bf16)v.z; o[3] = (bf16)v.w;
    *(bf16x4*)dst = o;
  }
}

// ---------------- assemble V transposed: vT[hk][128][3072] bf16 -------------
__global__ __launch_bounds__(256) void k_assemble_vT(
    const float* __restrict__ xp0, const float* __restrict__ xp1,
    const float* __restrict__ cv, bf16* __restrict__ vT,
    const int* __restrict__ seqstarts, const int* __restrict__ kvstarts,
    const int* __restrict__ cachestarts, const int* __restrict__ start_pos) {
  __shared__ float tile[64][130];
  int hk = blockIdx.y, p0 = blockIdx.x * 64;
  int tid = threadIdx.x;
  {
    int r = tid >> 2;
    int p = p0 + r;
    int b = 0;
    for (int i = 1; i < 4; ++i) if (kvstarts[i] <= p) b = i;
    int pkv = p - kvstarts[b];
    int f0 = (tid & 3) * 32;
    if (pkv >= start_pos[b]) {
      int tn = seqstarts[b] + pkv - start_pos[b];
      size_t base = (size_t)tn * 6144 + (40 + hk) * 128;
#pragma unroll
      for (int i = 0; i < 8; ++i) {
        float4 v0 = *(const float4*)(xp0 + base + f0 + i * 4);
        float4 v1 = *(const float4*)(xp1 + base + f0 + i * 4);
        tile[r][f0 + i * 4 + 0] = v0.x + v1.x;
        tile[r][f0 + i * 4 + 1] = v0.y + v1.y;
        tile[r][f0 + i * 4 + 2] = v0.z + v1.z;
        tile[r][f0 + i * 4 + 3] = v0.w + v1.w;
      }
    } else {
      int ci = cachestarts[b] + pkv;
      const float* src = cv + ((size_t)ci * 8 + hk) * 128;
#pragma unroll
      for (int i = 0; i < 8; ++i) {
        float4 v = *(const float4*)(src + f0 + i * 4);
        tile[r][f0 + i * 4 + 0] = v.x; tile[r][f0 + i * 4 + 1] = v.y;
        tile[r][f0 + i * 4 + 2] = v.z; tile[r][f0 + i * 4 + 3] = v.w;
      }
    }
  }
  __syncthreads();
  int d = tid >> 1, hf = tid & 1;
  bf16* dst = vT + ((size_t)hk * 128 + d) * 3072 + p0 + hf * 32;
#pragma unroll
  for (int q = 0; q < 4; ++q) {
    bf16x8 o;
#pragma unroll
    for (int e = 0; e < 8; ++e) o[e] = (bf16)tile[hf * 32 + q * 8 + e][d];
    *(bf16x8*)(dst + q * 8) = o;
  }
}

// ---------------- flash attention (MFMA, swizzled LDS) ----------------
// qb[1024][32][128], kall[8][3072][128], vT[8][128][3072] -> aout[1024][4096]
// LDS swizzle: slot (r,c) holds global chunk c ^ (r&15) [Ks] / c ^ (r&7)
// [Vs,Ps]; all fragment ds_read_b128 become 2-way (free). Q lives in regs.
__global__ __launch_bounds__(256, 4) void k_attn(
    const bf16* __restrict__ qb, const bf16* __restrict__ kall,
    const bf16* __restrict__ vT, bf16* __restrict__ aout,
    const int* __restrict__ seqstarts, const int* __restrict__ kvstarts,
    const int* __restrict__ start_pos) {
  __shared__ bf16 Ks[64 * 128];
  __shared__ bf16 Vs[128 * 64];
  __shared__ bf16 Ps[64 * 64];
  int qbi = blockIdx.x, h = blockIdx.y, hk = h >> 2;
  int t0 = qbi * 64;
  int s = 0;
  for (int i = 1; i < 4; ++i) if (seqstarts[i] <= t0) s = i;
  int posbase = t0 - seqstarts[s] + start_pos[s];  // pos of query row 0
  int kv0 = kvstarts[s];
  int nkv = posbase + 64;  // keys needed (multiple of 64 by construction)
  int tid = threadIdx.x, w = tid >> 6, lane = tid & 63;
  int lq = lane >> 4, l16 = lane & 15;

  // Q fragments straight to registers (row = w*16+l16, chunk = kk*4+lq)
  bf16x8 qa[4];
#pragma unroll
  for (int kk = 0; kk < 4; ++kk)
    qa[kk] = *(const bf16x8*)(qb + (((size_t)(t0 + w * 16 + l16) * 32 + h) * 128 +
                                    kk * 32 + lq * 8));

  // staging swizzles (wave-uniform base rows are multiples of the mask span)
  int krow = lane >> 4;                                    // +0..3
  int kchunk = ((lane & 15) ^ krow) ;                       // ^ (r&15) partial
  int vrow = lane >> 3;                                    // +0..7
  int vchunk = ((lane & 7) ^ (vrow & 7));
  int sw8 = l16 & 7;                                       // read-side swizzles

  float m_r[4], l_r[4];
  floatx4 oacc[8] = {};
#pragma unroll
  for (int rg = 0; rg < 4; ++rg) { m_r[rg] = -3.0e38f; l_r[rg] = 0.f; }
  const float scale = 0.08838834764831845f;

  for (int p0 = 0; p0 < nkv; p0 += 64) {
#pragma unroll
    for (int c = 0; c < 4; ++c) {
      int base_r = w * 16 + c * 4;                  // wave-uniform
      int r = base_r + krow;
      int gch = (lane & 15) ^ ((c * 4 + krow) & 15);  // full r&15 (w*16%16==0)
      LDS_ASYNC16(kall + (((size_t)hk * 3072 + kv0 + p0 + r) * 128 + gch * 8),
                  &Ks[base_r * 128]);
    }
#pragma unroll
    for (int c = 0; c < 4; ++c) {
      int base_d = w * 32 + c * 8;                  // wave-uniform
      int d = base_d + vrow;
      LDS_ASYNC16(vT + (((size_t)hk * 128 + d) * 3072 + kv0 + p0 + vchunk * 8),
                  &Vs[base_d * 64]);
    }
    __syncthreads();

    // S = Q K^T : wave w owns 16 query rows [w*16, w*16+16)
    floatx4 sacc[4] = {};
#pragma unroll
    for (int kk = 0; kk < 4; ++kk)
#pragma unroll
      for (int j = 0; j < 4; ++j) {
        bf16x8 kb = *(const bf16x8*)&Ks[(j * 16 + l16) * 128 +
                                        ((kk * 4 + lq) ^ l16) * 8];
        sacc[j] = __builtin_amdgcn_mfma_f32_16x16x32_bf16(qa[kk], kb, sacc[j], 0, 0, 0);
      }

    // online softmax; lane holds S[row=lq*4+rg][col=j*16+l16]
#pragma unroll
    for (int rg = 0; rg < 4; ++rg) {
      int qpos = posbase + w * 16 + lq * 4 + rg;
      float sv[4];
      float rmax = -3.0e38f;
#pragma unroll
      for (int j = 0; j < 4; ++j) {
        int pkv = p0 + j * 16 + l16;
        sv[j] = (pkv <= qpos) ? sacc[j][rg] * scale : -3.0e38f;
        rmax = fmaxf(rmax, sv[j]);
      }
#pragma unroll
      for (int off = 1; off < 16; off <<= 1)
        rmax = fmaxf(rmax, __shfl_xor(rmax, off, 64));
      float mnew = fmaxf(m_r[rg], rmax);
      float alpha = __expf(m_r[rg] - mnew);
      m_r[rg] = mnew;
      int prow = w * 16 + lq * 4 + rg;
      int pswz = (lq * 4 + rg) & 7;
      float psum = 0.f;
#pragma unroll
      for (int j = 0; j < 4; ++j) {
        float pv = __expf(sv[j] - mnew);
        psum += pv;
        int chunk = (j * 2 + (l16 >> 3)) ^ pswz;
        Ps[prow * 64 + chunk * 8 + (l16 & 7)] = (bf16)pv;
      }
#pragma unroll
      for (int off = 1; off < 16; off <<= 1) psum += __shfl_xor(psum, off, 64);
      l_r[rg] = l_r[rg] * alpha + psum;
#pragma unroll
      for (int nt = 0; nt < 8; ++nt) oacc[nt][rg] *= alpha;
    }

    // O += P V  (P rows of wave w only read by wave w -> no barrier needed)
#pragma unroll
    for (int kk = 0; kk < 2; ++kk) {
      bf16x8 pa = *(const bf16x8*)&Ps[(w * 16 + l16) * 64 +
                                      ((kk * 4 + lq) ^ sw8) * 8];
#pragma unroll
      for (int nt = 0; nt < 8; ++nt) {
        bf16x8 vb = *(const bf16x8*)&Vs[(nt * 16 + l16) * 64 +
                                        ((kk * 4 + lq) ^ sw8) * 8];
        oacc[nt] = __builtin_amdgcn_mfma_f32_16x16x32_bf16(pa, vb, oacc[nt], 0, 0, 0);
      }
    }
    __syncthreads();
  }

  // epilogue: write attn output bf16 [t][h*128+d]
#pragma unroll
  for (int rg = 0; rg < 4; ++rg) {
    float inv = 1.0f / l_r[rg];
    int t = t0 + w * 16 + lq * 4 + rg;
#pragma unroll
    for (int nt = 0; nt < 8; ++nt)
      aout[(size_t)t * 4096 + h * 128 + nt * 16 + l16] =
          (bf16)(oacc[nt][rg] * inv);
  }
}

// ---------------- host launcher ----------------
extern "C" void kernel_launch(void* const* d_in, const int* in_sizes, int n_in,
                              void* d_out, int out_size, void* d_ws, size_t ws_size,
                              hipStream_t stream) {
  const float* x = (const float*)d_in[0];
  const float* wqkv = (const float*)d_in[1];
  const float* wo = (const float*)d_in[2];
  const float* kv = (const float*)d_in[3];
  const int* seqstarts = (const int*)d_in[4];
  const int* kvstarts = (const int*)d_in[5];
  const int* cachestarts = (const int*)d_in[6];
  const int* start_pos = (const int*)d_in[7];
  float* out = (float*)d_out;

  char* base = (char*)d_ws;
  size_t off = 0;
  auto carve = [&](size_t bytes) {
    void* r = base + off;
    off += (bytes + 255) & ~(size_t)255;
    return r;
  };
  bf16* x_bf    = (bf16*)carve(1024ull * 4096 * 2);
  bf16* wqkvT   = (bf16*)carve(6144ull * 4096 * 2);
  bf16* woT     = (bf16*)carve(4096ull * 4096 * 2);
  float* xqkv   = (float*)carve(2ull * 1024 * 6144 * 4);  // 2 split-K partials
  bf16* q_bf    = (bf16*)carve(1024ull * 32 * 128 * 2);
  bf16* xk_bf   = (bf16*)carve(1024ull * 8 * 128 * 2);
  bf16* k_all   = (bf16*)carve(8ull * 3072 * 128 * 2);
  bf16* vT_all  = (bf16*)carve(8ull * 128 * 3072 * 2);
  bf16* attn_bf = (bf16*)carve(1024ull * 4096 * 2);
  // GEMM2 split-K partials alias wqkvT (48 MB >= 2*16.8 MB); wqkvT is dead
  // after GEMM1, which strictly precedes GEMM2 on the stream.
  float* outp = (float*)wqkvT;

  float* xqkv1 = xqkv + 1024ull * 6144;
  const float* cache_v = kv + 8192ull * 8 * 128;  // kv_cache[0,1]

  k_cvt<<<4096, 256, 0, stream>>>(x, x_bf);
  k_transpose_cvt<<<dim3(96, 64), 256, 0, stream>>>(wqkv, wqkvT, 4096, 6144);
  k_transpose_cvt<<<dim3(64, 64), 256, 0, stream>>>(wo, woT, 4096, 4096);
  k_gemm_bt<<<dim3(48, 8, 2), 256, 0, stream>>>(x_bf, wqkvT, xqkv, 1024, 6144,
                                                4096, 2);
  k_rope<<<1024, 256, 0, stream>>>(xqkv, xqkv1, q_bf, xk_bf, seqstarts, start_pos);
  k_assemble_k<<<3072, 256, 0, stream>>>(xk_bf, kv, k_all, seqstarts, kvstarts,
                                         cachestarts, start_pos);
  k_assemble_vT<<<dim3(48, 8), 256, 0, stream>>>(xqkv, xqkv1, cache_v, vT_all,
                                                 seqstarts, kvstarts, cachestarts,
                                                 start_pos);
  k_attn<<<dim3(16, 32), 256, 0, stream>>>(q_bf, k_all, vT_all, attn_bf,
                                           seqstarts, kvstarts, start_pos);
  k_gemm_bt<<<dim3(32, 8, 2), 256, 0, stream>>>(attn_bf, woT, outp, 1024, 4096,
                                                4096, 2);
  k_merge<<<4096, 256, 0, stream>>>(outp, outp + 1024ull * 4096, out);
}

// Round 4
// 497.973 us; speedup vs baseline: 1.0386x; 1.0386x over previous
//
#include <hip/hip_runtime.h>
#include <hip/hip_bf16.h>
#include <math.h>
#include <stdint.h>

typedef __bf16 bf16;
typedef __attribute__((ext_vector_type(4))) float floatx4;
typedef __attribute__((ext_vector_type(8))) bf16 bf16x8;
typedef __attribute__((ext_vector_type(4))) bf16 bf16x4;

#define LDS_ASYNC16(gptr, lptr)                                                \
  __builtin_amdgcn_global_load_lds(                                            \
      (const __attribute__((address_space(1))) void*)(gptr),                   \
      (__attribute__((address_space(3))) void*)(lptr), 16, 0, 0)

// ---------------- elementwise fp32 -> bf16 ----------------
__global__ __launch_bounds__(256) void k_cvt(const float* __restrict__ in,
                                             bf16* __restrict__ out) {
  int i = (blockIdx.x * 256 + threadIdx.x) * 4;
  float4 v = *(const float4*)(in + i);
  bf16x4 o;
  o[0] = (bf16)v.x; o[1] = (bf16)v.y; o[2] = (bf16)v.z; o[3] = (bf16)v.w;
  *(bf16x4*)(out + i) = o;
}

// ---------------- merge two fp32 partials ----------------
__global__ __launch_bounds__(256) void k_merge(const float* __restrict__ a,
                                               const float* __restrict__ b,
                                               float* __restrict__ out) {
  int i = (blockIdx.x * 256 + threadIdx.x) * 4;
  float4 va = *(const float4*)(a + i);
  float4 vb = *(const float4*)(b + i);
  float4 o;
  o.x = va.x + vb.x; o.y = va.y + vb.y; o.z = va.z + vb.z; o.w = va.w + vb.w;
  *(float4*)(out + i) = o;
}

// ---------------- transpose + convert: in[K][N] f32 -> out[N][K] bf16 -------
__global__ __launch_bounds__(256) void k_transpose_cvt(const float* __restrict__ in,
                                                       bf16* __restrict__ out,
                                                       int K, int N) {
  __shared__ float tile[64][65];
  int k0 = blockIdx.y * 64, n0 = blockIdx.x * 64;
  int tid = threadIdx.x;
  int cg = tid & 15, rr = tid >> 4;
#pragma unroll
  for (int p = 0; p < 4; ++p) {
    int r = rr + p * 16;
    float4 v = *(const float4*)(in + (size_t)(k0 + r) * N + n0 + cg * 4);
    tile[r][cg * 4 + 0] = v.x; tile[r][cg * 4 + 1] = v.y;
    tile[r][cg * 4 + 2] = v.z; tile[r][cg * 4 + 3] = v.w;
  }
  __syncthreads();
#pragma unroll
  for (int p = 0; p < 4; ++p) {
    int n = rr + p * 16;
    bf16x4 o;
    o[0] = (bf16)tile[cg * 4 + 0][n];
    o[1] = (bf16)tile[cg * 4 + 1][n];
    o[2] = (bf16)tile[cg * 4 + 2][n];
    o[3] = (bf16)tile[cg * 4 + 3][n];
    *(bf16x4*)(out + (size_t)(n0 + n) * K + k0 + cg * 4) = o;
  }
}

// ---------------- GEMM split-K: A[M][K] bf16 @ B[N][K] bf16 -----------------
// 128x128 tile, BK=32, LDS chunk-swizzled so fragment ds_read_b128 is 2-way.
__global__ __launch_bounds__(256) void k_gemm_bt(const bf16* __restrict__ A,
                                                 const bf16* __restrict__ B,
                                                 float* __restrict__ C,
                                                 int M, int N, int K, int ksplit) {
  __shared__ bf16 As[128 * 32];
  __shared__ bf16 Bs[128 * 32];
  int tid = threadIdx.x;
  int w = tid >> 6, lane = tid & 63;
  int lq = lane >> 4, l16 = lane & 15;
  int bm = blockIdx.y * 128, bn = blockIdx.x * 128;
  int wm = (w >> 1) * 64, wn = (w & 1) * 64;
  int kc = K / ksplit;
  int koff = blockIdx.z * kc;
  C += (size_t)blockIdx.z * M * N;
  floatx4 acc[4][4] = {};
  const bf16* Ab = A + (size_t)bm * K;
  const bf16* Bb = B + (size_t)bn * K;
  int srow = (lane >> 2);                               // 16 rows / instr
  int scol = (((lane & 3) ^ ((srow >> 1) & 3))) * 8;    // swizzled 16B chunk
  int sa = (l16 >> 1) & 3;                              // read-side swizzle

  for (int k0 = koff; k0 < koff + kc; k0 += 32) {
#pragma unroll
    for (int c = 0; c < 2; ++c) {
      int r = w * 32 + c * 16 + srow;
      LDS_ASYNC16(Ab + (size_t)r * K + k0 + scol, &As[(w * 32 + c * 16) * 32]);
      LDS_ASYNC16(Bb + (size_t)r * K + k0 + scol, &Bs[(w * 32 + c * 16) * 32]);
    }
    __syncthreads();
    bf16x8 af[4], bfr[4];
#pragma unroll
    for (int i = 0; i < 4; ++i)
      af[i] = *(const bf16x8*)&As[(wm + i * 16 + l16) * 32 + (lq ^ sa) * 8];
#pragma unroll
    for (int j = 0; j < 4; ++j)
      bfr[j] = *(const bf16x8*)&Bs[(wn + j * 16 + l16) * 32 + (lq ^ sa) * 8];
#pragma unroll
    for (int i = 0; i < 4; ++i)
#pragma unroll
      for (int j = 0; j < 4; ++j)
        acc[i][j] = __builtin_amdgcn_mfma_f32_16x16x32_bf16(af[i], bfr[j],
                                                            acc[i][j], 0, 0, 0);
    __syncthreads();
  }
  // C/D layout: col = lane&15, row = (lane>>4)*4 + reg  [m89-verified]
#pragma unroll
  for (int i = 0; i < 4; ++i)
#pragma unroll
    for (int j = 0; j < 4; ++j) {
      int m = bm + wm + i * 16 + lq * 4;
      int n = bn + wn + j * 16 + l16;
      float* cp = C + (size_t)m * N + n;
#pragma unroll
      for (int r = 0; r < 4; ++r) cp[(size_t)r * N] = acc[i][j][r];
    }
}

// ---------------- RoPE on Q and K heads of xqkv (sums 2 partials) -----------
__global__ __launch_bounds__(256) void k_rope(const float* __restrict__ xp0,
                                              const float* __restrict__ xp1,
                                              bf16* __restrict__ qb,
                                              bf16* __restrict__ kb,
                                              const int* __restrict__ seqstarts,
                                              const int* __restrict__ start_pos) {
  int t = blockIdx.x;
  int s = 0;
  for (int i = 1; i < 4; ++i) if (seqstarts[i] <= t) s = i;
  float pos = (float)(t - seqstarts[s] + start_pos[s]);
  for (int wk = threadIdx.x; wk < 40 * 64; wk += 256) {
    int hh = wk >> 6, j = wk & 63;
    size_t idx = ((size_t)t * 48 + hh) * 128 + 2 * j;
    float2 a0 = *(const float2*)(xp0 + idx);
    float2 a1 = *(const float2*)(xp1 + idx);
    float x1 = a0.x + a1.x;
    float x2 = a0.y + a1.y;
    float invf = exp2f(-(float)j * 0.20762050593045935f);
    float ang = pos * invf;
    float sv, cv;
    sincosf(ang, &sv, &cv);
    float r1 = x1 * cv - x2 * sv;
    float r2 = x1 * sv + x2 * cv;
    unsigned int u1 = (unsigned int)__builtin_bit_cast(unsigned short, (bf16)r1);
    unsigned int u2 = (unsigned int)__builtin_bit_cast(unsigned short, (bf16)r2);
    unsigned int pk = u1 | (u2 << 16);
    unsigned int* dst = (hh < 32)
        ? (unsigned int*)(qb + ((size_t)t * 32 + hh) * 128)
        : (unsigned int*)(kb + ((size_t)t * 8 + (hh - 32)) * 128);
    dst[j] = pk;
  }
}

// ---------------- assemble K: kall[hk][3072][128] bf16 ----------------
__global__ __launch_bounds__(256) void k_assemble_k(
    const bf16* __restrict__ xk, const float* __restrict__ ck,
    bf16* __restrict__ kall,
    const int* __restrict__ seqstarts, const int* __restrict__ kvstarts,
    const int* __restrict__ cachestarts, const int* __restrict__ start_pos) {
  int p = blockIdx.x;  // 0..3071
  int b = 0;
  for (int i = 1; i < 4; ++i) if (kvstarts[i] <= p) b = i;
  int pkv = p - kvstarts[b];
  int tid = threadIdx.x;
  int hk = tid >> 5, d4 = (tid & 31) * 4;
  bf16* dst = kall + ((size_t)hk * 3072 + p) * 128 + d4;
  if (pkv >= start_pos[b]) {
    int tn = seqstarts[b] + pkv - start_pos[b];
    *(bf16x4*)dst = *(const bf16x4*)(xk + ((size_t)tn * 8 + hk) * 128 + d4);
  } else {
    int ci = cachestarts[b] + pkv;
    float4 v = *(const float4*)(ck + ((size_t)ci * 8 + hk) * 128 + d4);
    bf16x4 o;
    o[0] = (bf16)v.x; o[1] = (bf16)v.y; o[2] = (bf16)v.z; o[3] = (bf16)v.w;
    *(bf16x4*)dst = o;
  }
}

// ---------------- assemble V transposed: vT[hk][128][3072] bf16 -------------
__global__ __launch_bounds__(256) void k_assemble_vT(
    const float* __restrict__ xp0, const float* __restrict__ xp1,
    const float* __restrict__ cv, bf16* __restrict__ vT,
    const int* __restrict__ seqstarts, const int* __restrict__ kvstarts,
    const int* __restrict__ cachestarts, const int* __restrict__ start_pos) {
  __shared__ float tile[64][130];
  int hk = blockIdx.y, p0 = blockIdx.x * 64;
  int tid = threadIdx.x;
  {
    int r = tid >> 2;
    int p = p0 + r;
    int b = 0;
    for (int i = 1; i < 4; ++i) if (kvstarts[i] <= p) b = i;
    int pkv = p - kvstarts[b];
    int f0 = (tid & 3) * 32;
    if (pkv >= start_pos[b]) {
      int tn = seqstarts[b] + pkv - start_pos[b];
      size_t base = (size_t)tn * 6144 + (40 + hk) * 128;
#pragma unroll
      for (int i = 0; i < 8; ++i) {
        float4 v0 = *(const float4*)(xp0 + base + f0 + i * 4);
        float4 v1 = *(const float4*)(xp1 + base + f0 + i * 4);
        tile[r][f0 + i * 4 + 0] = v0.x + v1.x;
        tile[r][f0 + i * 4 + 1] = v0.y + v1.y;
        tile[r][f0 + i * 4 + 2] = v0.z + v1.z;
        tile[r][f0 + i * 4 + 3] = v0.w + v1.w;
      }
    } else {
      int ci = cachestarts[b] + pkv;
      const float* src = cv + ((size_t)ci * 8 + hk) * 128;
#pragma unroll
      for (int i = 0; i < 8; ++i) {
        float4 v = *(const float4*)(src + f0 + i * 4);
        tile[r][f0 + i * 4 + 0] = v.x; tile[r][f0 + i * 4 + 1] = v.y;
        tile[r][f0 + i * 4 + 2] = v.z; tile[r][f0 + i * 4 + 3] = v.w;
      }
    }
  }
  __syncthreads();
  int d = tid >> 1, hf = tid & 1;
  bf16* dst = vT + ((size_t)hk * 128 + d) * 3072 + p0 + hf * 32;
#pragma unroll
  for (int q = 0; q < 4; ++q) {
    bf16x8 o;
#pragma unroll
    for (int e = 0; e < 8; ++e) o[e] = (bf16)tile[hf * 32 + q * 8 + e][d];
    *(bf16x8*)(dst + q * 8) = o;
  }
}

// ---------------- flash attention, split-KV (MFMA, swizzled LDS) ------------
// Each block = (qbi, head, seg): 512-key segment, <=8 chunks of 64 keys.
// Writes unnormalized partial O (fp32) + (m,l) per row; k_attn_merge combines.
__global__ __launch_bounds__(256) void k_attn(
    const bf16* __restrict__ qb, const bf16* __restrict__ kall,
    const bf16* __restrict__ vT, float* __restrict__ pO,
    float2* __restrict__ pml,
    const int* __restrict__ seqstarts, const int* __restrict__ kvstarts,
    const int* __restrict__ start_pos) {
  __shared__ bf16 Ks[64 * 128];
  __shared__ bf16 Vs[128 * 64];
  __shared__ bf16 Ps[64 * 64];
  int qbi = blockIdx.x, h = blockIdx.y, seg = blockIdx.z, hk = h >> 2;
  int t0 = qbi * 64;
  int s = 0;
  for (int i = 1; i < 4; ++i) if (seqstarts[i] <= t0) s = i;
  int posbase = t0 - seqstarts[s] + start_pos[s];  // pos of query row 0
  int kv0 = kvstarts[s];
  int nkv = posbase + 64;        // keys needed (multiple of 64)
  int pbeg = seg * 512;
  if (pbeg >= nkv) return;       // inactive segment
  int pend = min(pbeg + 512, nkv);
  int tid = threadIdx.x, w = tid >> 6, lane = tid & 63;
  int lq = lane >> 4, l16 = lane & 15;

  // Q fragments straight to registers (row = w*16+l16, chunk = kk*4+lq)
  bf16x8 qa[4];
#pragma unroll
  for (int kk = 0; kk < 4; ++kk)
    qa[kk] = *(const bf16x8*)(qb + (((size_t)(t0 + w * 16 + l16) * 32 + h) * 128 +
                                    kk * 32 + lq * 8));

  // staging swizzles (wave-uniform base rows are multiples of the mask span)
  int krow = lane >> 4;                                    // +0..3
  int vrow = lane >> 3;                                    // +0..7
  int vchunk = ((lane & 7) ^ (vrow & 7));
  int sw8 = l16 & 7;                                       // read-side swizzle

  float m_r[4], l_r[4];
  floatx4 oacc[8] = {};
#pragma unroll
  for (int rg = 0; rg < 4; ++rg) { m_r[rg] = -3.0e38f; l_r[rg] = 0.f; }
  const float scale = 0.08838834764831845f;

  for (int p0 = pbeg; p0 < pend; p0 += 64) {
#pragma unroll
    for (int c = 0; c < 4; ++c) {
      int base_r = w * 16 + c * 4;                  // wave-uniform
      int r = base_r + krow;
      int gch = (lane & 15) ^ ((c * 4 + krow) & 15);
      LDS_ASYNC16(kall + (((size_t)hk * 3072 + kv0 + p0 + r) * 128 + gch * 8),
                  &Ks[base_r * 128]);
    }
#pragma unroll
    for (int c = 0; c < 4; ++c) {
      int base_d = w * 32 + c * 8;                  // wave-uniform
      int d = base_d + vrow;
      LDS_ASYNC16(vT + (((size_t)hk * 128 + d) * 3072 + kv0 + p0 + vchunk * 8),
                  &Vs[base_d * 64]);
    }
    __syncthreads();

    // S = Q K^T : wave w owns 16 query rows [w*16, w*16+16)
    floatx4 sacc[4] = {};
#pragma unroll
    for (int kk = 0; kk < 4; ++kk)
#pragma unroll
      for (int j = 0; j < 4; ++j) {
        bf16x8 kb = *(const bf16x8*)&Ks[(j * 16 + l16) * 128 +
                                        ((kk * 4 + lq) ^ l16) * 8];
        sacc[j] = __builtin_amdgcn_mfma_f32_16x16x32_bf16(qa[kk], kb, sacc[j], 0, 0, 0);
      }

    // online softmax; lane holds S[row=lq*4+rg][col=j*16+l16]
#pragma unroll
    for (int rg = 0; rg < 4; ++rg) {
      int qpos = posbase + w * 16 + lq * 4 + rg;
      float sv[4];
      float rmax = -3.0e38f;
#pragma unroll
      for (int j = 0; j < 4; ++j) {
        int pkv = p0 + j * 16 + l16;
        sv[j] = (pkv <= qpos) ? sacc[j][rg] * scale : -3.0e38f;
        rmax = fmaxf(rmax, sv[j]);
      }
#pragma unroll
      for (int off = 1; off < 16; off <<= 1)
        rmax = fmaxf(rmax, __shfl_xor(rmax, off, 64));
      float mnew = fmaxf(m_r[rg], rmax);
      float alpha = __expf(m_r[rg] - mnew);
      m_r[rg] = mnew;
      int prow = w * 16 + lq * 4 + rg;
      int pswz = (lq * 4 + rg) & 7;
      float psum = 0.f;
#pragma unroll
      for (int j = 0; j < 4; ++j) {
        float pv = __expf(sv[j] - mnew);
        psum += pv;
        int chunk = (j * 2 + (l16 >> 3)) ^ pswz;
        Ps[prow * 64 + chunk * 8 + (l16 & 7)] = (bf16)pv;
      }
#pragma unroll
      for (int off = 1; off < 16; off <<= 1) psum += __shfl_xor(psum, off, 64);
      l_r[rg] = l_r[rg] * alpha + psum;
#pragma unroll
      for (int nt = 0; nt < 8; ++nt) oacc[nt][rg] *= alpha;
    }

    // O += P V  (P rows of wave w only read by wave w -> no barrier needed)
#pragma unroll
    for (int kk = 0; kk < 2; ++kk) {
      bf16x8 pa = *(const bf16x8*)&Ps[(w * 16 + l16) * 64 +
                                      ((kk * 4 + lq) ^ sw8) * 8];
#pragma unroll
      for (int nt = 0; nt < 8; ++nt) {
        bf16x8 vb = *(const bf16x8*)&Vs[(nt * 16 + l16) * 64 +
                                        ((kk * 4 + lq) ^ sw8) * 8];
        oacc[nt] = __builtin_amdgcn_mfma_f32_16x16x32_bf16(pa, vb, oacc[nt], 0, 0, 0);
      }
    }
    __syncthreads();
  }

  // epilogue: write unnormalized partial O (fp32) + per-row (m,l)
  size_t obase = (((size_t)seg * 16 + qbi) * 32 + h) * 8192;
#pragma unroll
  for (int rg = 0; rg < 4; ++rg) {
    int row = w * 16 + lq * 4 + rg;
#pragma unroll
    for (int nt = 0; nt < 8; ++nt)
      pO[obase + (size_t)row * 128 + nt * 16 + l16] = oacc[nt][rg];
    if (l16 == 0)
      pml[(((size_t)seg * 16 + qbi) * 32 + h) * 64 + row] =
          make_float2(m_r[rg], l_r[rg]);
  }
}

// ---------------- merge split-KV partials -> attn_bf ----------------
__global__ __launch_bounds__(256) void k_attn_merge(
    const float* __restrict__ pO, const float2* __restrict__ pml,
    bf16* __restrict__ aout,
    const int* __restrict__ seqstarts, const int* __restrict__ start_pos) {
  int qbi = blockIdx.x, h = blockIdx.y;
  int t0 = qbi * 64;
  int s = 0;
  for (int i = 1; i < 4; ++i) if (seqstarts[i] <= t0) s = i;
  int nkv = t0 - seqstarts[s] + start_pos[s] + 64;
  int ns = (nkv + 511) >> 9;   // <= 3 segments
  int tid = threadIdx.x;
  int row = tid >> 2, cg = (tid & 3) * 32;
  float2 ml[3];
  float w[3];
  float mstar = -3.0e38f;
  for (int si = 0; si < ns; ++si) {
    ml[si] = pml[(((size_t)si * 16 + qbi) * 32 + h) * 64 + row];
    mstar = fmaxf(mstar, ml[si].x);
  }
  float denom = 0.f;
  for (int si = 0; si < ns; ++si) {
    w[si] = __expf(ml[si].x - mstar);
    denom += w[si] * ml[si].y;
  }
  float inv = 1.0f / denom;
  bf16* dst = aout + (size_t)(t0 + row) * 4096 + h * 128 + cg;
#pragma unroll
  for (int c = 0; c < 32; c += 8) {
    float acc[8] = {};
    for (int si = 0; si < ns; ++si) {
      const float* src = pO + (((size_t)si * 16 + qbi) * 32 + h) * 8192 +
                         (size_t)row * 128 + cg + c;
      float4 v0 = *(const float4*)(src);
      float4 v1 = *(const float4*)(src + 4);
      acc[0] += w[si] * v0.x; acc[1] += w[si] * v0.y;
      acc[2] += w[si] * v0.z; acc[3] += w[si] * v0.w;
      acc[4] += w[si] * v1.x; acc[5] += w[si] * v1.y;
      acc[6] += w[si] * v1.z; acc[7] += w[si] * v1.w;
    }
    bf16x8 o;
#pragma unroll
    for (int e = 0; e < 8; ++e) o[e] = (bf16)(acc[e] * inv);
    *(bf16x8*)(dst + c) = o;
  }
}

// ---------------- host launcher ----------------
extern "C" void kernel_launch(void* const* d_in, const int* in_sizes, int n_in,
                              void* d_out, int out_size, void* d_ws, size_t ws_size,
                              hipStream_t stream) {
  const float* x = (const float*)d_in[0];
  const float* wqkv = (const float*)d_in[1];
  const float* wo = (const float*)d_in[2];
  const float* kv = (const float*)d_in[3];
  const int* seqstarts = (const int*)d_in[4];
  const int* kvstarts = (const int*)d_in[5];
  const int* cachestarts = (const int*)d_in[6];
  const int* start_pos = (const int*)d_in[7];
  float* out = (float*)d_out;

  char* base = (char*)d_ws;
  size_t off = 0;
  auto carve = [&](size_t bytes) {
    void* r = base + off;
    off += (bytes + 255) & ~(size_t)255;
    return r;
  };
  bf16* x_bf    = (bf16*)carve(1024ull * 4096 * 2);
  bf16* wqkvT   = (bf16*)carve(6144ull * 4096 * 2);
  bf16* woT     = (bf16*)carve(4096ull * 4096 * 2);
  float* xqkv   = (float*)carve(2ull * 1024 * 6144 * 4);  // 2 split-K partials
  bf16* q_bf    = (bf16*)carve(1024ull * 32 * 128 * 2);
  bf16* xk_bf   = (bf16*)carve(1024ull * 8 * 128 * 2);
  bf16* k_all   = (bf16*)carve(8ull * 3072 * 128 * 2);
  bf16* vT_all  = (bf16*)carve(8ull * 128 * 3072 * 2);
  bf16* attn_bf = (bf16*)carve(1024ull * 4096 * 2);
  float2* pml   = (float2*)carve(3ull * 16 * 32 * 64 * 8);
  // GEMM2 split-K partials alias wqkvT (48 MB >= 2*16.8 MB); wqkvT is dead
  // after GEMM1. Attention partial-O (3*16*32*64*128 fp32 = 50.3 MB) aliases
  // xqkv, dead after k_rope/k_assemble_vT. All consumers are stream-ordered.
  float* outp = (float*)wqkvT;
  float* pO = xqkv;

  float* xqkv1 = xqkv + 1024ull * 6144;
  const float* cache_v = kv + 8192ull * 8 * 128;  // kv_cache[0,1]

  k_cvt<<<4096, 256, 0, stream>>>(x, x_bf);
  k_transpose_cvt<<<dim3(96, 64), 256, 0, stream>>>(wqkv, wqkvT, 4096, 6144);
  k_transpose_cvt<<<dim3(64, 64), 256, 0, stream>>>(wo, woT, 4096, 4096);
  k_gemm_bt<<<dim3(48, 8, 2), 256, 0, stream>>>(x_bf, wqkvT, xqkv, 1024, 6144,
                                                4096, 2);
  k_rope<<<1024, 256, 0, stream>>>(xqkv, xqkv1, q_bf, xk_bf, seqstarts, start_pos);
  k_assemble_k<<<3072, 256, 0, stream>>>(xk_bf, kv, k_all, seqstarts, kvstarts,
                                         cachestarts, start_pos);
  k_assemble_vT<<<dim3(48, 8), 256, 0, stream>>>(xqkv, xqkv1, cache_v, vT_all,
                                                 seqstarts, kvstarts, cachestarts,
                                                 start_pos);
  // split-KV attention: pO overwrites xqkv (dead from here on)
  k_attn<<<dim3(16, 32, 3), 256, 0, stream>>>(q_bf, k_all, vT_all, pO, pml,
                                              seqstarts, kvstarts, start_pos);
  k_attn_merge<<<dim3(16, 32), 256, 0, stream>>>(pO, pml, attn_bf, seqstarts,
                                                 start_pos);
  k_gemm_bt<<<dim3(32, 8, 2), 256, 0, stream>>>(attn_bf, woT, outp, 1024, 4096,
                                                4096, 2);
  k_merge<<<4096, 256, 0, stream>>>(outp, outp + 1024ull * 4096, out);
}